// Round 9
// baseline (80.542 us; speedup 1.0000x reference)
//
#include <hip/hip_runtime.h>

// Problem geometry: B=8, H=512, W=512, HID=64, T=16.
#define HH 512
#define WW 512
#define WPR 16                     // u32 words per global row
#define RO 16                      // owned rows per evolve block
#define HALO 15                    // T-1 steps of temporal blocking
#define ROWS (RO + 2 * HALO)       // 46 rows staged in LDS
#define FRAME_WORDS (8 * HH * WPR) // 65536 u32 per bit-frame (B=8)

// lgkm-only barrier (verified round 7): waits only on LDS ops; global stores
// stay in flight across steps.
#define STEP_BARRIER() do {                                   \
    asm volatile("s_waitcnt lgkmcnt(0)" ::: "memory");        \
    __builtin_amdgcn_s_barrier();                             \
    __builtin_amdgcn_sched_barrier(0);                        \
} while (0)

// ---------------------------------------------------------------------------
// Kernel 1 "evolve": 256 blocks (8 images x 32 row-groups) x 768 threads.
// Per block:
//  (a) 512-entry rule (exact fp32, same add order as reference einsum --
//      verified absmax 0.0 rounds 1-8) + 4096-entry pair-LUT (1 KiB).
//  (b) bit-pack its 46-row FULL-WIDTH f0 slab via wave-aligned ballots
//      (no column halo -> wrap in W is exact); owned rows also copy f0
//      verbatim to out[0].
//  (c) 15 steps, lgkm-only barrier each; all state in LDS. 44 valid rows x
//      16 words = 704 tasks -> one per thread. After each step, store the
//      owned 16x16 words (1 KiB, coalesced) to the global bit-frame.
// ---------------------------------------------------------------------------
__global__ __launch_bounds__(768) void evolve(const float* __restrict__ f0,
                                              const float* __restrict__ W1,
                                              const float* __restrict__ b1,
                                              const float* __restrict__ W2,
                                              const float* __restrict__ b2,
                                              int hid,
                                              float* __restrict__ out,
                                              unsigned int* __restrict__ fields) {
    __shared__ unsigned int rule[512];
    __shared__ unsigned int lutp[256];
    __shared__ unsigned int bufA[ROWS * WPR];
    __shared__ unsigned int bufB[ROWS * WPR];

    const int tid = threadIdx.x;
    const int rg = blockIdx.x & 31;
    const int b  = blockIdx.x >> 5;
    const int r0 = rg * RO;          // first owned global row

    // (a) rule table — byte-identical math to the verified build.
    if (tid < 512) {
        int p = tid;
        float logit = b2[0];
        for (int k = 0; k < hid; ++k) {
            float a = b1[k];
#pragma unroll
            for (int nn = 0; nn < 9; ++nn)
                if (p & (1 << nn)) a += W1[nn * hid + k];
            logit += fmaxf(a, 0.0f) * W2[k];
        }
        rule[p] = (logit > 0.0f) ? 1u : 0u;
    }
    __syncthreads();

    // pair-LUT: idx12 = u4 | m4<<4 | d4<<8 -> 2 bits (cells c, c+1).
    if (tid < 256) {
        unsigned int wv = 0;
#pragma unroll
        for (int k = 0; k < 16; ++k) {
            unsigned int e = (unsigned int)tid * 16u + k;
            unsigned int u = e & 15u, mm = (e >> 4) & 15u, d = (e >> 8) & 15u;
            unsigned int i0 = (u & 7u) | ((mm & 7u) << 3) | ((d & 7u) << 6);
            unsigned int i1 = (u >> 1) | ((mm >> 1) << 3) | ((d >> 1) << 6);
            wv |= (rule[i0] | (rule[i1] << 1)) << (2 * k);
        }
        lutp[tid] = wv;
    }

    // (b) pack 46x512 f0 slab + frame-0 verbatim copy of owned rows.
    // i strides 768 (wave-multiple); col base of each wave is 64-aligned and
    // 512%64==0, so no wave straddles a row; last pass activates exactly 512
    // threads = 8 full waves. Ballot-split verified in round 6 (absmax 0).
    {
        const float* f0b = f0 + (size_t)b * (HH * WW);
        float* out0 = out + (size_t)b * (HH * WW);
        const int lane = tid & 63;
        for (int i = tid; i < ROWS * WW; i += 768) {
            int l = i >> 9, c = i & 511;
            int gr = (r0 - HALO + l) & (HH - 1);
            float v = f0b[(size_t)gr * WW + c];
            unsigned long long m = __ballot(v > 0.5f);
            if (lane == 0)  bufA[l * WPR + (c >> 5)] = (unsigned int)m;
            if (lane == 32) bufA[l * WPR + (c >> 5)] = (unsigned int)(m >> 32);
            if (l >= HALO && l < HALO + RO)
                out0[(size_t)gr * WW + c] = v;
        }
    }
    __syncthreads();

    unsigned int* oldb = bufA;
    unsigned int* newb = bufB;

    // (c) 15 steps, LDS-only; full-width wrap in W (verified round 1/2).
    for (int s = 1; s <= HALO; ++s) {
        const int lq = tid >> 4;
        const int w  = tid & 15;
        const int l  = s + lq;
        if (l < ROWS - s) {               // <= 704 active threads
            const unsigned int* Ru = oldb + (l - 1) * WPR;
            const unsigned int* Rm = oldb + l * WPR;
            const unsigned int* Rd = oldb + (l + 1) * WPR;
            const int wl = (w + 15) & 15, wn = (w + 1) & 15;
            unsigned long long eu = ((((unsigned long long)Ru[wn] << 32) | Ru[w]) << 1) | (Ru[wl] >> 31);
            unsigned long long em = ((((unsigned long long)Rm[wn] << 32) | Rm[w]) << 1) | (Rm[wl] >> 31);
            unsigned long long ed = ((((unsigned long long)Rd[wn] << 32) | Rd[w]) << 1) | (Rd[wl] >> 31);
            unsigned int ow = 0;
#pragma unroll
            for (int j = 0; j < 16; ++j) {
                unsigned int idx = (unsigned int)((eu >> (2 * j)) & 15ull)
                                 | ((unsigned int)((em >> (2 * j)) & 15ull) << 4)
                                 | ((unsigned int)((ed >> (2 * j)) & 15ull) << 8);
                ow |= ((lutp[idx >> 4] >> ((idx & 15u) * 2)) & 3u) << (2 * j);
            }
            newb[l * WPR + w] = ow;
        }
        STEP_BARRIER();    // newb complete; oldb reads done (lgkm only).

        // store owned 16x16 words of frame s (1 KiB, coalesced); the ds_reads
        // complete by the next barrier, 2 steps before this buffer is reused.
        if (tid < RO * WPR) {
            int lr = tid >> 4, w2 = tid & 15;
            fields[(size_t)(s - 1) * FRAME_WORDS + b * (HH * WPR)
                   + (size_t)(r0 + lr) * WPR + w2] = newb[(HALO + lr) * WPR + w2];
        }
        unsigned int* tmp = oldb; oldb = newb; newb = tmp;
    }
}

// ---------------------------------------------------------------------------
// Kernel 2 "expand": pure streaming, no LDS, no barriers. 15360 blocks x 512
// threads; one float4 per thread. Word fetch shared by 8 consecutive lanes
// (broadcast); stores 1 KiB contiguous per wave — fillBuffer-like pattern.
// ---------------------------------------------------------------------------
__global__ __launch_bounds__(512) void expand(const unsigned int* __restrict__ fields,
                                              float* __restrict__ out, int n) {
    const int f  = blockIdx.x >> 10;                         // frame-1 (0..14)
    const int g4 = ((blockIdx.x & 1023) << 9) + threadIdx.x; // f4 idx in frame
    unsigned int wv = fields[(size_t)f * FRAME_WORDS + (g4 >> 3)];
    unsigned int nib = (wv >> ((g4 & 7) * 4)) & 15u;
    float4 v;
    v.x = (float)(nib & 1u);
    v.y = (float)((nib >> 1) & 1u);
    v.z = (float)((nib >> 2) & 1u);
    v.w = (float)(nib >> 3);
    ((float4*)out)[(size_t)(f + 1) * (n >> 2) + g4] = v;
}

// ---------------------------------------------------------------------------
// Launch: evolve -> expand (2 dispatches).
// d_ws: [0, 15*FRAME_WORDS*4) = 3.93 MB of bit-frames for steps 1..15.
// ---------------------------------------------------------------------------
extern "C" void kernel_launch(void* const* d_in, const int* in_sizes, int n_in,
                              void* d_out, int out_size, void* d_ws, size_t ws_size,
                              hipStream_t stream) {
    const float* f0 = (const float*)d_in[0];
    const float* W1 = (const float*)d_in[1];
    const float* b1 = (const float*)d_in[2];
    const float* W2 = (const float*)d_in[3];
    const float* b2 = (const float*)d_in[4];
    float* out = (float*)d_out;

    const int n = in_sizes[0];        // B*1*H*W = 2,097,152
    const int hid = in_sizes[2];      // 64

    unsigned int* fields = (unsigned int*)d_ws;

    evolve<<<256, 768, 0, stream>>>(f0, W1, b1, W2, b2, hid, out, fields);
    expand<<<15 * 1024, 512, 0, stream>>>(fields, out, n);
}

// Round 10
// 62.877 us; speedup vs baseline: 1.2809x; 1.2809x over previous
//
#include <hip/hip_runtime.h>

// Problem geometry: B=8, H=512, W=512, HID=64, T=16.
#define HH 512
#define WW 512
#define WPR 16                    // u32 words per global row
#define RO 16                     // owned rows per block
#define HALO 15                   // T-1 steps of temporal blocking
#define ROWS (RO + 2 * HALO)      // 46 rows staged in LDS
#define OW 8                      // owned words per block (256 cols)
#define TW 10                     // tile words = owned + 1 halo word each side
// Halo-word correctness: dependency cone grows 1 bit/step; clamp garbage in
// the +/-1 halo words never reaches owned bits (verified rounds 2,3,4,6,7,8).

// lgkm-only barrier (verified rounds 7/8): waits only on LDS ops; global
// float stores stay in flight across steps.
#define STEP_BARRIER() do {                                   \
    asm volatile("s_waitcnt lgkmcnt(0)" ::: "memory");        \
    __builtin_amdgcn_s_barrier();                             \
    __builtin_amdgcn_sched_barrier(0);                        \
} while (0)

// ---------------------------------------------------------------------------
// Kernel 1: out[0]=f0 verbatim; bit-pack (f0>0.5) into field (verified R8).
// Blocks 0..63 additionally build the 64K-entry quad-LUT into ws:
//   entry e (16 bits) = 4-bit col-windows a,b,c,d of rows (l-1,l,l+1,l+2);
//   bit0 = rule(a,b,c @cols 0-2)  -> cell (row l,   col 2j)
//   bit1 = rule(a,b,c @cols 1-3)  -> cell (row l,   col 2j+1)
//   bit2 = rule(b,c,d @cols 0-2)  -> cell (row l+1, col 2j)
//   bit3 = rule(b,c,d @cols 1-3)  -> cell (row l+1, col 2j+1)
// 8 entries packed per u32 -> 8192 u32 = 32 KiB. Rule math byte-identical to
// the build verified absmax 0.0 in rounds 1-8.
// ---------------------------------------------------------------------------
__global__ __launch_bounds__(512) void init_pack(const float* __restrict__ f0,
                                                 const float* __restrict__ W1,
                                                 const float* __restrict__ b1,
                                                 const float* __restrict__ W2,
                                                 const float* __restrict__ b2,
                                                 int hid,
                                                 float* __restrict__ out,
                                                 unsigned long long* __restrict__ field,
                                                 unsigned int* __restrict__ lut16g) {
    __shared__ unsigned int rule[512];
    const int tid = threadIdx.x;
    int c = blockIdx.x * 512 + tid;
    float v = f0[c];
    out[c] = v;
    unsigned long long m = __ballot(v > 0.5f);
    if ((tid & 63) == 0) field[c >> 6] = m;

    if (blockIdx.x < 64) {
        {   // rule table — byte-identical math to the verified build.
            int p = tid;  // 0..511
            float logit = b2[0];
            for (int k = 0; k < hid; ++k) {
                float a = b1[k];
#pragma unroll
                for (int nn = 0; nn < 9; ++nn)
                    if (p & (1 << nn)) a += W1[nn * hid + k];
                logit += fmaxf(a, 0.0f) * W2[k];
            }
            rule[p] = (logit > 0.0f) ? 1u : 0u;
        }
        __syncthreads();
        if (tid < 128) {   // this block's 128-word slice of the quad-LUT
            int word = blockIdx.x * 128 + tid;
            unsigned int wv = 0;
#pragma unroll
            for (int k = 0; k < 8; ++k) {
                unsigned int e = (unsigned int)word * 8u + k;
                unsigned int a = e & 15u, b = (e >> 4) & 15u;
                unsigned int cc = (e >> 8) & 15u, d = (e >> 12) & 15u;
                unsigned int bit0 = rule[(a & 7u) | ((b & 7u) << 3) | ((cc & 7u) << 6)];
                unsigned int bit1 = rule[((a >> 1) & 7u) | (((b >> 1) & 7u) << 3) | (((cc >> 1) & 7u) << 6)];
                unsigned int bit2 = rule[(b & 7u) | ((cc & 7u) << 3) | ((d & 7u) << 6)];
                unsigned int bit3 = rule[((b >> 1) & 7u) | (((cc >> 1) & 7u) << 3) | (((d >> 1) & 7u) << 6)];
                wv |= (bit0 | (bit1 << 1) | (bit2 << 2) | (bit3 << 3)) << (4 * k);
            }
            lut16g[word] = wv;
        }
    }
}

// ---------------------------------------------------------------------------
// Kernel 2: 512 blocks (8 images x 32 row-groups x 2 col-groups) x 512 thr.
// Preamble: 32 KiB quad-LUT load (L2->LDS) + 46x10-word tile load. 15 steps:
// row-PAIR tasks ((23-t)*10 <= 220, one per thread), each task computes 64
// cells (2 rows x 32 cols) via 16 quad-LUT lookups; lgkm-only barrier; then
// in-loop float4 emission (2 per thread, verified R3 pattern) streaming while
// the next step computes.
// ---------------------------------------------------------------------------
__global__ __launch_bounds__(512) void mega(const unsigned int* __restrict__ field,
                                            const unsigned int* __restrict__ lut16g,
                                            float* __restrict__ out,
                                            int n, int T) {
    __shared__ alignas(16) unsigned int lut16[8192];   // 32 KiB
    __shared__ unsigned int bufA[ROWS * TW];
    __shared__ unsigned int bufB[ROWS * TW];

    const int tid = threadIdx.x;
    const int cg = blockIdx.x & 1;
    const int rg = (blockIdx.x >> 1) & 31;
    const int b  = blockIdx.x >> 6;
    const int r0 = rg * RO;          // first owned global row
    const int q0 = cg * OW;          // first owned global word
    const int c0 = cg * (OW * 32);   // first owned global column

    // quad-LUT: 2048 uint4 loads (4 iterations, coalesced; L2-broadcast).
    for (int i = tid; i < 2048; i += 512)
        ((uint4*)lut16)[i] = ((const uint4*)lut16g)[i];
    // bit tile load (wrap in H via &511, in W via &15) — verified R3/R8.
    {
        const unsigned int* F = field + b * (HH * WPR);
        for (int i = tid; i < ROWS * TW; i += 512) {
            int l = i / TW, tw = i - l * TW;
            int g  = (r0 - HALO + l) & (HH - 1);
            int gw = (q0 - 1 + tw) & (WPR - 1);
            bufA[i] = F[g * WPR + gw];
        }
    }
    __syncthreads();

    unsigned int* oldb = bufA;
    unsigned int* newb = bufB;
    float* outb = out + (size_t)b * (HH * WW);

    for (int t = 1; t < T; ++t) {
        // row-pair tasks: pairs tile valid rows [t, 46-t) (even count 46-2t).
        const int npairs = 23 - t;
        if (tid < npairs * TW) {
            const int pr = tid / TW;
            const int w  = tid - pr * TW;
            const int l  = t + 2 * pr;                  // first output row
            const unsigned int* Ra = oldb + (l - 1) * TW;
            const unsigned int* Rb = oldb + l * TW;
            const unsigned int* Rc = oldb + (l + 1) * TW;
            const unsigned int* Rd = oldb + (l + 2) * TW;
            const int wl = (w == 0) ? 0 : w - 1;        // garbage-safe (cone)
            const int wn = (w == TW - 1) ? TW - 1 : w + 1;
            unsigned long long ea = ((((unsigned long long)Ra[wn] << 32) | Ra[w]) << 1) | (Ra[wl] >> 31);
            unsigned long long eb = ((((unsigned long long)Rb[wn] << 32) | Rb[w]) << 1) | (Rb[wl] >> 31);
            unsigned long long ec = ((((unsigned long long)Rc[wn] << 32) | Rc[w]) << 1) | (Rc[wl] >> 31);
            unsigned long long ed = ((((unsigned long long)Rd[wn] << 32) | Rd[w]) << 1) | (Rd[wl] >> 31);
            unsigned int owb = 0, owc = 0;
#pragma unroll
            for (int j = 0; j < 16; ++j) {
                unsigned int idx = (unsigned int)((ea >> (2 * j)) & 15ull)
                                 | ((unsigned int)((eb >> (2 * j)) & 15ull) << 4)
                                 | ((unsigned int)((ec >> (2 * j)) & 15ull) << 8)
                                 | ((unsigned int)((ed >> (2 * j)) & 15ull) << 12);
                unsigned int ent = (lut16[idx >> 3] >> ((idx & 7u) * 4)) & 15u;
                owb |= (ent & 3u) << (2 * j);
                owc |= ((ent >> 2) & 3u) << (2 * j);
            }
            newb[l * TW + w] = owb;
            newb[(l + 1) * TW + w] = owc;
        }
        STEP_BARRIER();    // lgkm-only: newb complete, oldb reads done;
                           // frame stores from previous steps stay in flight.

        // emit step t: owned 16 rows x 256 cols, 2 passes of 512 float4
        // (verified R3 pattern). Overlaps next step's compute (writes oldb
        // only); ds_reads of newb complete by the NEXT barrier, one full step
        // before newb is reused.
        float* outt = outb + (size_t)t * n;
#pragma unroll
        for (int rep = 0; rep < 2; ++rep) {
            int cell = (rep * 512 + tid) * 4;           // 0..4092, step 4
            int lr  = cell >> 8;                        // owned row 0..15
            int col = cell & 255;                       // owned col
            unsigned int wv = newb[(HALO + lr) * TW + 1 + (col >> 5)];
            unsigned int nib = (wv >> (col & 31)) & 15u;
            float4 v;
            v.x = (float)(nib & 1u);
            v.y = (float)((nib >> 1) & 1u);
            v.z = (float)((nib >> 2) & 1u);
            v.w = (float)(nib >> 3);
            *(float4*)(outt + (size_t)(r0 + lr) * WW + c0 + col) = v;
        }
        unsigned int* tmp = oldb; oldb = newb; newb = tmp;
    }
}

// ---------------------------------------------------------------------------
// Launch: init_pack -> mega (2 dispatches).
// d_ws: [0, 32768)              quad-LUT (8192 u32)
//       [32768, 32768 + n/8)    packed step-0 bit field (256 KiB)
// ---------------------------------------------------------------------------
extern "C" void kernel_launch(void* const* d_in, const int* in_sizes, int n_in,
                              void* d_out, int out_size, void* d_ws, size_t ws_size,
                              hipStream_t stream) {
    const float* f0 = (const float*)d_in[0];
    const float* W1 = (const float*)d_in[1];
    const float* b1 = (const float*)d_in[2];
    const float* W2 = (const float*)d_in[3];
    const float* b2 = (const float*)d_in[4];
    float* out = (float*)d_out;

    const int n = in_sizes[0];        // B*1*H*W = 2,097,152
    const int hid = in_sizes[2];      // 64
    const int T = out_size / n;       // 16
    const int B = n / (HH * WW);      // 8

    char* ws = (char*)d_ws;
    unsigned int* lut16g = (unsigned int*)ws;
    unsigned long long* fld = (unsigned long long*)(ws + 32768);

    init_pack<<<n / 512, 512, 0, stream>>>(f0, W1, b1, W2, b2, hid, out, fld, lut16g);
    mega<<<B * (HH / RO) * 2, 512, 0, stream>>>((const unsigned int*)fld, lut16g,
                                                out, n, T);
}